// Round 1
// baseline (299.518 us; speedup 1.0000x reference)
//
#include <hip/hip_runtime.h>
#include <hip/hip_bf16.h>
#include <math.h>

#define B   256
#define IU  8
#define IC  1152
#define NU  10
#define US  16

// ---------------- s pass ----------------
// s[b,d,u] = sum_{c,i} cT[d,c] * W[c,d,u,i] * x[b,i,c]
// grid 512 = 16 b-tiles (BT=16) x 32 c-chunks (CCH=36). Partials to sp[ch][b][d][u].
#define CCH 36
#define BT  16

__global__ __launch_bounds__(256) void s_pass(const float* __restrict__ x,
                                              const float* __restrict__ W,
                                              const float* __restrict__ cT,
                                              float* __restrict__ sp) {
    __shared__ float xs[IU * BT * CCH];   // [i][bl][cc]
    __shared__ float cl[NU * CCH];        // [d][cc]
    const int tid = threadIdx.x;
    const int bt = blockIdx.x & 15;
    const int ch = blockIdx.x >> 4;
    const int b0 = bt * BT, c0 = ch * CCH;

    // stage x[b0..b0+15, :, c0..c0+35] -> xs[i][bl][cc] (identity mapping, coalesced-ish, conflict-free writes)
    for (int idx = tid; idx < IU * BT * CCH; idx += 256) {
        int cc = idx % CCH;
        int r = idx / CCH;
        int bl = r % BT;
        int i = r / BT;
        xs[idx] = x[((b0 + bl) * IU + i) * IC + c0 + cc];
    }
    float scale;
    if (cT) {
        for (int idx = tid; idx < NU * CCH; idx += 256) {
            int d = idx / CCH, cc = idx % CCH;
            cl[idx] = cT[d * IC + c0 + cc];
        }
        scale = 1.0f;
    } else {
        // first iteration: softmax(0) is uniform 1/IC
        for (int idx = tid; idx < NU * CCH; idx += 256) cl[idx] = 1.0f;
        scale = 1.0f / (float)IC;
    }
    __syncthreads();

    const int uq = tid & 15;        // unit index u
    const int bq = tid >> 4;        // local batch
    const int b = b0 + bq;

    float acc[NU];
#pragma unroll
    for (int d = 0; d < NU; d++) acc[d] = 0.0f;

    for (int cc = 0; cc < CCH; cc++) {
        const int c = c0 + cc;
        float xv[IU];
#pragma unroll
        for (int i = 0; i < IU; i++) xv[i] = xs[(i * BT + bq) * CCH + cc];  // bq*36 stride -> 2-way (free)
        const float4* wp = (const float4*)(W + (size_t)c * (NU * US * IU) + uq * IU);
#pragma unroll
        for (int d = 0; d < NU; d++) {
            float4 w0 = wp[d * 32 + 0];   // W[c][d][uq][0..3]
            float4 w1 = wp[d * 32 + 1];   // W[c][d][uq][4..7]
            float uh = w0.x * xv[0] + w0.y * xv[1] + w0.z * xv[2] + w0.w * xv[3]
                     + w1.x * xv[4] + w1.y * xv[5] + w1.z * xv[6] + w1.w * xv[7];
            acc[d] += cl[d * CCH + cc] * uh;
        }
    }
#pragma unroll
    for (int d = 0; d < NU; d++)
        sp[(((size_t)ch * B + b) * NU + d) * US + uq] = acc[d] * scale;
}

// ---------------- squash ----------------
// reduce 32 c-chunk partials, then v[b,d,u] = s * msq/((1+msq)*sqrt(msq)), msq = sum_d s^2 (per b,u)
__global__ __launch_bounds__(192) void squash_k(const float* __restrict__ sp,
                                                float* __restrict__ vout) {
    __shared__ float smag[NU * US];
    const int b = blockIdx.x;
    const int tid = threadIdx.x;
    const int d = tid >> 4, uq = tid & 15;
    float s = 0.0f;
    if (d < NU) {
        for (int chp = 0; chp < 32; chp++)
            s += sp[(((size_t)chp * B + b) * NU + d) * US + uq];
        smag[d * US + uq] = s * s;
    }
    __syncthreads();
    if (d < NU) {
        float msq = 0.0f;
#pragma unroll
        for (int dd = 0; dd < NU; dd++) msq += smag[dd * US + uq];
        float f = msq / ((1.0f + msq) * sqrtf(msq));
        vout[((size_t)b * NU + d) * US + uq] = s * f;
    }
}

// ---------------- agree pass ----------------
// agree[c,d] = (1/B) sum_{b,u} (sum_i W[c,d,u,i]*x[b,i,c]) * v[b,d,u]
// grid 2880 = 36 c-tiles (32c) x 10 d x 8 b-chunks (32b). Partials to ap[bch][d][c].
#define ACT 32
#define ABT 32

__global__ __launch_bounds__(256) void agree_k(const float* __restrict__ x,
                                               const float* __restrict__ W,
                                               const float* __restrict__ v,
                                               float* __restrict__ ap) {
    __shared__ float xs[IU * ABT * ACT];  // [i][bl][cl]
    __shared__ float wl[ACT * 129];       // [c][u*8+i], pad 129 breaks bank stride
    __shared__ float vl[ABT * 17];        // [b][u], pad 17
    __shared__ float red[8 * 33];
    const int tid = threadIdx.x;
    const int bx = blockIdx.x;
    const int ct = bx % 36;
    const int r = bx / 36;
    const int d = r % NU;
    const int bch = r / NU;
    const int c0 = ct * ACT, b0 = bch * ABT;

    for (int idx = tid; idx < IU * ABT * ACT; idx += 256) {
        int cl_ = idx & 31, bl = (idx >> 5) & 31, i = idx >> 10;
        xs[idx] = x[((b0 + bl) * IU + i) * IC + c0 + cl_];
    }
    for (int idx = tid; idx < ACT * US * IU; idx += 256) {
        int c = idx >> 7, k = idx & 127;
        wl[c * 129 + k] = W[(size_t)(c0 + c) * (NU * US * IU) + d * US * IU + k];
    }
    for (int idx = tid; idx < ABT * US; idx += 256) {
        int bl = idx >> 4, u = idx & 15;
        vl[bl * 17 + u] = v[((size_t)(b0 + bl) * NU + d) * US + u];
    }
    __syncthreads();

    const int cl_ = tid & 31;   // channel within tile
    const int bg = tid >> 5;    // batch group (4 b each)

    float xv[4][IU];
#pragma unroll
    for (int bb = 0; bb < 4; bb++)
#pragma unroll
        for (int i = 0; i < IU; i++)
            xv[bb][i] = xs[(i * ABT + bg * 4 + bb) * ACT + cl_];

    float acc = 0.0f;
#pragma unroll
    for (int u = 0; u < US; u++) {
        float w[IU];
#pragma unroll
        for (int i = 0; i < IU; i++) w[i] = wl[cl_ * 129 + u * IU + i];
#pragma unroll
        for (int bb = 0; bb < 4; bb++) {
            float uh = 0.0f;
#pragma unroll
            for (int i = 0; i < IU; i++) uh += w[i] * xv[bb][i];
            acc += uh * vl[(bg * 4 + bb) * 17 + u];
        }
    }
    red[bg * 33 + cl_] = acc;
    __syncthreads();
    if (tid < ACT) {
        float s = 0.0f;
#pragma unroll
        for (int g = 0; g < 8; g++) s += red[g * 33 + tid];
        ap[((size_t)bch * NU + d) * IC + c0 + tid] = s;
    }
}

// ---------------- b update + softmax over channels ----------------
// one block per d; reduces 8 agree partials, b += agree, cT[d,c] = softmax_c(b[d,c])
__global__ __launch_bounds__(384) void bsm_k(const float* __restrict__ ap,
                                             float* __restrict__ bij,
                                             float* __restrict__ cT,
                                             int first) {
    __shared__ float wred[8];
    __shared__ float bcast;
    const int d = blockIdx.x;
    const int tid = threadIdx.x;
    float bn[3];
    float lmax = -1e30f;
#pragma unroll
    for (int k = 0; k < 3; k++) {
        int c = tid + k * 384;
        float a = 0.0f;
#pragma unroll
        for (int g = 0; g < 8; g++) a += ap[((size_t)g * NU + d) * IC + c];
        a *= (1.0f / (float)B);
        float bo = first ? 0.0f : bij[d * IC + c];
        bn[k] = bo + a;
        bij[d * IC + c] = bn[k];
        lmax = fmaxf(lmax, bn[k]);
    }
    for (int off = 32; off > 0; off >>= 1) lmax = fmaxf(lmax, __shfl_down(lmax, off, 64));
    const int wid = tid >> 6, lane = tid & 63;
    if (lane == 0) wred[wid] = lmax;
    __syncthreads();
    if (tid == 0) {
        float m = wred[0];
        for (int w_ = 1; w_ < 6; w_++) m = fmaxf(m, wred[w_]);
        bcast = m;
    }
    __syncthreads();
    const float mx = bcast;
    float e[3];
    float lsum = 0.0f;
#pragma unroll
    for (int k = 0; k < 3; k++) { e[k] = expf(bn[k] - mx); lsum += e[k]; }
    for (int off = 32; off > 0; off >>= 1) lsum += __shfl_down(lsum, off, 64);
    if (lane == 0) wred[wid] = lsum;
    __syncthreads();
    if (tid == 0) {
        float s2 = 0.0f;
        for (int w_ = 0; w_ < 6; w_++) s2 += wred[w_];
        bcast = 1.0f / s2;
    }
    __syncthreads();
    const float inv = bcast;
#pragma unroll
    for (int k = 0; k < 3; k++) cT[d * IC + tid + k * 384] = e[k] * inv;
}

extern "C" void kernel_launch(void* const* d_in, const int* in_sizes, int n_in,
                              void* d_out, int out_size, void* d_ws, size_t ws_size,
                              hipStream_t stream) {
    const float* x = (const float*)d_in[0];   // [256, 8, 1152]
    const float* W = (const float*)d_in[1];   // [1, 1152, 10, 16, 8]
    float* out = (float*)d_out;               // [256, 10, 16] fp32

    // workspace layout (floats): total ~5.9 MB
    float* sp  = (float*)d_ws;                // 32 * 256 * 10 * 16 = 1,310,720
    float* v   = sp + (size_t)32 * B * NU * US;  // 40,960
    float* bij = v + (size_t)B * NU * US;        // 11,520  [d][c]
    float* cT  = bij + (size_t)NU * IC;          // 11,520  [d][c]
    float* apg = cT + (size_t)NU * IC;           // 8*10*1152 = 92,160

    // iteration 1 (c uniform = 1/1152)
    s_pass<<<512, 256, 0, stream>>>(x, W, nullptr, sp);
    squash_k<<<B, 192, 0, stream>>>(sp, v);
    agree_k<<<2880, 256, 0, stream>>>(x, W, v, apg);
    bsm_k<<<NU, 384, 0, stream>>>(apg, bij, cT, 1);
    // iteration 2
    s_pass<<<512, 256, 0, stream>>>(x, W, cT, sp);
    squash_k<<<B, 192, 0, stream>>>(sp, v);
    agree_k<<<2880, 256, 0, stream>>>(x, W, v, apg);
    bsm_k<<<NU, 384, 0, stream>>>(apg, bij, cT, 0);
    // iteration 3 (agree not needed after final squash)
    s_pass<<<512, 256, 0, stream>>>(x, W, cT, sp);
    squash_k<<<B, 192, 0, stream>>>(sp, out);
}